// Round 2
// baseline (701.901 us; speedup 1.0000x reference)
//
#include <hip/hip_runtime.h>

typedef unsigned int   u32;
typedef unsigned short u16;

// ---------- bf16 helpers (intermediates are stored as bf16 in d_ws) ----------
__device__ __forceinline__ float bfs(u16 u) {
  union { u32 i; float f; } v; v.i = ((u32)u) << 16; return v.f;
}
__device__ __forceinline__ u16 f2bf(float f) {
  union { float f; u32 i; } v; v.f = f;
  u32 r = v.i + 0x7fffu + ((v.i >> 16) & 1u);   // round-to-nearest-even
  return (u16)(r >> 16);
}

// dot of a 64-elem f32 row (16B-aligned) with 64 f32 values in LDS
__device__ __forceinline__ float dot64f(const float* __restrict__ w, const float* __restrict__ x) {
  const float4* w4 = (const float4*)w;
  float acc = 0.f;
#pragma unroll
  for (int i = 0; i < 16; ++i) {
    float4 v = w4[i];
    const float* xx = x + i * 4;
    acc += v.x * xx[0] + v.y * xx[1] + v.z * xx[2] + v.w * xx[3];
  }
  return acc;
}

// ---------------- Kernel 1: per-token projections ----------------
// grid = B*T blocks, 256 threads. Computes logA, silu(XBC)->X/B/C, gate.
__global__ __launch_bounds__(256) void k_proj(
    const float* __restrict__ inp,
    const float* __restrict__ W_logA, const float* __restrict__ b_logA,
    const float* __restrict__ W_XBC,  const float* __restrict__ b_XBC,
    const float* __restrict__ W_gate, const float* __restrict__ b_gate,
    u16* __restrict__ Xs, u16* __restrict__ Bms, u16* __restrict__ Cms,
    u16* __restrict__ gates, float* __restrict__ logAs)
{
  int bt = blockIdx.x;
  int b = bt >> 10, t = bt & 1023;
  int tid = threadIdx.x;
  __shared__ float xs[1024];
  {
    const float4* xin = (const float4*)(inp + (size_t)bt * 1024);
    float4 v = xin[tid];
    xs[4 * tid + 0] = v.x;
    xs[4 * tid + 1] = v.y;
    xs[4 * tid + 2] = v.z;
    xs[4 * tid + 3] = v.w;
  }
  __syncthreads();
  // per (b,t): H * (1 logA + 192 XBC + 64 gate) = 16*257 = 4112 dot products
  for (int u = tid; u < 16 * 257; u += 256) {
    int h = u / 257;
    int o = u - h * 257;
    const float* xh = xs + h * 64;
    if (o == 0) {
      float acc = dot64f(W_logA + h * 64, xh) + b_logA[h];
      logAs[(b * 16 + h) * 1024 + t] = acc;
    } else if (o <= 192) {
      int oo = o - 1;
      float acc = dot64f(W_XBC + (size_t)(h * 192 + oo) * 64, xh) + b_XBC[h * 192 + oo];
      float s = acc / (1.f + __expf(-acc));   // silu
      int n = oo & 63;
      size_t base = (((size_t)(b * 16 + h)) * 1024 + t) * 64 + n;  // (b,h,t,n)
      u16 sv = f2bf(s);
      if (oo < 64)       Xs[base]  = sv;
      else if (oo < 128) Bms[base] = sv;
      else               Cms[base] = sv;
    } else {
      int oo = o - 193;
      float acc = dot64f(W_gate + (size_t)(h * 64 + oo) * 64, xh) + b_gate[h * 64 + oo];
      gates[(((size_t)(b * 1024 + t)) * 16 + h) * 64 + oo] = f2bf(acc);  // (b,t,h,c)
    }
  }
}

// ---------------- Kernel 2: inclusive cumsum over T per (b,h) ----------------
__global__ __launch_bounds__(1024) void k_scan(float* __restrict__ logAs)
{
  int bh = blockIdx.x;      // 32 rows
  int t  = threadIdx.x;     // 1024 threads
  __shared__ float buf0[1024], buf1[1024];
  buf0[t] = logAs[bh * 1024 + t];
  __syncthreads();
  float* src = buf0; float* dst = buf1;
  for (int off = 1; off < 1024; off <<= 1) {
    float v = src[t];
    if (t >= off) v += src[t - off];
    dst[t] = v;
    __syncthreads();
    float* tmp = src; src = dst; dst = tmp;
  }
  logAs[bh * 1024 + t] = src[t];
}

// ---------------- Kernel 3: causal SSM attention (tiled 64x64) ----------------
// grid = (T/64, H, B), 256 threads; each thread owns a 4x4 patch of the Y tile.
__global__ __launch_bounds__(256) void k_ssm(
    const u16* __restrict__ Xs, const u16* __restrict__ Bms, const u16* __restrict__ Cms,
    const float* __restrict__ cum, const u16* __restrict__ gates, u16* __restrict__ Yg)
{
  int it = blockIdx.x, h = blockIdx.y, b = blockIdx.z;
  int bh = b * 16 + h;
  const u16* Xb   = Xs  + (size_t)bh * 1024 * 64;
  const u16* Bb   = Bms + (size_t)bh * 1024 * 64;
  const u16* Cb   = Cms + (size_t)bh * 1024 * 64;
  const float* cumb = cum + bh * 1024;
  int tid = threadIdx.x;
  int ty = tid >> 4, tx = tid & 15;

  __shared__ float Cts[64][65];
  __shared__ float Bts[64][65];
  __shared__ float Xts[64][65];
  __shared__ float Sts[64][65];
  __shared__ float cumi[64], cumj[64];

  float acc[4][4];
#pragma unroll
  for (int a = 0; a < 4; ++a)
#pragma unroll
    for (int c = 0; c < 4; ++c) acc[a][c] = 0.f;

  int i0 = it * 64;
  for (int k = tid; k < 4096; k += 256) {
    int r = k >> 6, c = k & 63;
    Cts[r][c] = bfs(Cb[(size_t)(i0 + r) * 64 + c]);
  }
  if (tid < 64) cumi[tid] = cumb[i0 + tid];
  __syncthreads();

  for (int jt = 0; jt <= it; ++jt) {
    int j0 = jt * 64;
    for (int k = tid; k < 4096; k += 256) {
      int r = k >> 6, c = k & 63;
      Bts[r][c] = bfs(Bb[(size_t)(j0 + r) * 64 + c]);
      Xts[r][c] = bfs(Xb[(size_t)(j0 + r) * 64 + c]);
    }
    if (tid < 64) cumj[tid] = cumb[j0 + tid];
    __syncthreads();

    // phase 1: S[i][j] = exp(cum_i - cum_j) * dot_n(C[i], B[j])  (causal mask)
    float sreg[4][4];
#pragma unroll
    for (int a = 0; a < 4; ++a)
#pragma unroll
      for (int c = 0; c < 4; ++c) sreg[a][c] = 0.f;
    for (int n = 0; n < 64; ++n) {
      float cv[4], bv[4];
#pragma unroll
      for (int a = 0; a < 4; ++a) cv[a] = Cts[ty * 4 + a][n];
#pragma unroll
      for (int c = 0; c < 4; ++c) bv[c] = Bts[tx * 4 + c][n];
#pragma unroll
      for (int a = 0; a < 4; ++a)
#pragma unroll
        for (int c = 0; c < 4; ++c) sreg[a][c] += cv[a] * bv[c];
    }
#pragma unroll
    for (int a = 0; a < 4; ++a) {
      int i = ty * 4 + a;
      float ci = cumi[i];
#pragma unroll
      for (int c = 0; c < 4; ++c) {
        int j = tx * 4 + c;
        // mask BEFORE multiply (no 0*inf path); clamp exp arg positive side
        float v;
        if (jt == it && j > i) {
          v = 0.f;
        } else {
          v = sreg[a][c] * __expf(fminf(ci - cumj[j], 30.f));
        }
        Sts[i][j] = v;
      }
    }
    __syncthreads();

    // phase 2: Y[i][c] += sum_j S[i][j] * X[j][c]
    for (int j = 0; j < 64; ++j) {
      float sv[4], xv[4];
#pragma unroll
      for (int a = 0; a < 4; ++a) sv[a] = Sts[ty * 4 + a][j];
#pragma unroll
      for (int c = 0; c < 4; ++c) xv[c] = Xts[j][tx * 4 + c];
#pragma unroll
      for (int a = 0; a < 4; ++a)
#pragma unroll
        for (int c = 0; c < 4; ++c) acc[a][c] += sv[a] * xv[c];
    }
    __syncthreads();
  }

  // epilogue: Yg = gate * Y, stored (B,T,D) as bf16
#pragma unroll
  for (int a = 0; a < 4; ++a) {
    int i = i0 + ty * 4 + a;
    ushort4 pv;
    float r[4];
#pragma unroll
    for (int c = 0; c < 4; ++c) {
      int cc = tx * 4 + c;
      float g = bfs(gates[(((size_t)(b * 1024 + i)) * 16 + h) * 64 + cc]);
      r[c] = acc[a][c] * g;
    }
    pv.x = f2bf(r[0]); pv.y = f2bf(r[1]); pv.z = f2bf(r[2]); pv.w = f2bf(r[3]);
    *(ushort4*)(Yg + ((size_t)(b * 1024 + i)) * 1024 + h * 64 + tx * 4) = pv;
  }
}

// ---------------- Kernel 4: out = Yg @ W_out^T + b_out ----------------
// M=2048, N=1024, K=1024. grid (32,16), 256 threads, 64x64 tile, 4x4/thread.
__global__ __launch_bounds__(256) void k_out(
    const u16* __restrict__ Yg, const float* __restrict__ Wout,
    const float* __restrict__ bout, float* __restrict__ out)
{
  int bm = blockIdx.x, bn = blockIdx.y;
  int tid = threadIdx.x;
  int ty = tid >> 4, tx = tid & 15;
  __shared__ float Yt[64][65];
  __shared__ float Wt[64][65];
  float acc[4][4];
#pragma unroll
  for (int a = 0; a < 4; ++a)
#pragma unroll
    for (int c = 0; c < 4; ++c) acc[a][c] = 0.f;

  int m0 = bm * 64, d0 = bn * 64;
  for (int kt = 0; kt < 16; ++kt) {
    int k0 = kt * 64;
    for (int k = tid; k < 4096; k += 256) {
      int r = k >> 6, c = k & 63;
      Yt[r][c] = bfs(Yg[(size_t)(m0 + r) * 1024 + k0 + c]);
      Wt[r][c] = Wout[(size_t)(d0 + r) * 1024 + k0 + c];
    }
    __syncthreads();
    for (int k = 0; k < 64; ++k) {
      float yv[4], wv[4];
#pragma unroll
      for (int a = 0; a < 4; ++a) yv[a] = Yt[ty * 4 + a][k];
#pragma unroll
      for (int c = 0; c < 4; ++c) wv[c] = Wt[tx * 4 + c][k];
#pragma unroll
      for (int a = 0; a < 4; ++a)
#pragma unroll
        for (int c = 0; c < 4; ++c) acc[a][c] += yv[a] * wv[c];
    }
    __syncthreads();
  }
#pragma unroll
  for (int a = 0; a < 4; ++a) {
    int m = m0 + ty * 4 + a;
    float4 pv;
    pv.x = acc[a][0] + bout[d0 + tx * 4 + 0];
    pv.y = acc[a][1] + bout[d0 + tx * 4 + 1];
    pv.z = acc[a][2] + bout[d0 + tx * 4 + 2];
    pv.w = acc[a][3] + bout[d0 + tx * 4 + 3];
    *(float4*)(out + (size_t)m * 1024 + d0 + tx * 4) = pv;
  }
}

// ---------------- host launcher ----------------
extern "C" void kernel_launch(void* const* d_in, const int* in_sizes, int n_in,
                              void* d_out, int out_size, void* d_ws, size_t ws_size,
                              hipStream_t stream)
{
  const float* inp   = (const float*)d_in[0];
  const float* WlogA = (const float*)d_in[1];
  const float* blogA = (const float*)d_in[2];
  const float* WXBC  = (const float*)d_in[3];
  const float* bXBC  = (const float*)d_in[4];
  const float* Wgate = (const float*)d_in[5];
  const float* bgate = (const float*)d_in[6];
  const float* Wout  = (const float*)d_in[7];
  const float* bout  = (const float*)d_in[8];
  float* out = (float*)d_out;

  // workspace: logAs f32 (32768 floats = 128 KiB), then 5 bf16 regions of
  // 2,097,152 u16 (4 MiB each) -> total ~20.1 MiB
  const size_t SZ = (size_t)2 * 16 * 1024 * 64;  // 2,097,152 elements
  float* logAs = (float*)d_ws;
  u16* base16  = (u16*)(logAs + 32768);
  u16* Xs    = base16;
  u16* Bms   = Xs + SZ;
  u16* Cms   = Bms + SZ;
  u16* gates = Cms + SZ;
  u16* Yg    = gates + SZ;

  k_proj<<<2048, 256, 0, stream>>>(inp, WlogA, blogA, WXBC, bXBC, Wgate, bgate,
                                   Xs, Bms, Cms, gates, logAs);
  k_scan<<<32, 1024, 0, stream>>>(logAs);
  k_ssm<<<dim3(16, 16, 2), 256, 0, stream>>>(Xs, Bms, Cms, logAs, gates, Yg);
  k_out<<<dim3(32, 16), 256, 0, stream>>>(Yg, Wout, bout, out);
}